// Round 1
// baseline (1478.993 us; speedup 1.0000x reference)
//
#include <hip/hip_runtime.h>
#include <hip/hip_bf16.h>
#include <hip/hip_fp16.h>

// GraphConvolution: out = segment_sum(vals[:,None] * support[cols], rows)
// N=100000 nodes, E=1600000 edges, F=128 features, fp32.
//
// Round 8: fuse phase2+gather into a per-bucket LDS-accumulating gather.
//  R7 counters: gather=62us but total=216us -> ~150us in binning (phase1+phase2).
//  phase2 only existed to build pairs[row*64+slot] for the deg-bounded gather.
//  New bucket_gather consumes coarse cells DIRECTLY: one block per
//  (256-row bucket, 64-feat half), float accum[256][64] in LDS (64KB, 2 blk/CU),
//  LDS fire-and-forget f32 atomics (cheap; far return-atomics remain banned per
//  R3/R5/R6), coalesced writeout. Deletes phase2 + pairs + cursor entirely.
//  Coarse record packed int4->int2 ((r&255)<<17 | c, val) -> half the bytes.
//  Rotate swizzle (col+r)&63 on accum avoids the 8-way bank conflict.

#define D_FEAT 128
#define F4 32            // float4s per feature vector
#define H4 32            // half4s per feature vector
#define STRIDE 64        // padded slots per row (fallback 1 only)
#define CELL 32          // slots per (bucket, block) cell (Poisson(21))
#define OVF_CAP 131072   // overflow list capacity
#define EPT 8            // edges per thread in phase 1
#define GU 4             // entries per group-iteration in bucket_gather

typedef float    vfloat4 __attribute__((ext_vector_type(4)));
typedef _Float16 half4v  __attribute__((ext_vector_type(4)));
typedef _Float16 half8v  __attribute__((ext_vector_type(8)));

// ============ phase 1: coarse bin (LDS ranks) + fused fp32->fp16 convert ============

__global__ __launch_bounds__(1024) void
phase1_bin_kernel(const float4* __restrict__ support4,
                  half8v* __restrict__ supporth,
                  const int* __restrict__ rows,
                  const int* __restrict__ cols,
                  const float* __restrict__ vals,
                  int2* __restrict__ coarse,     // [ND][NBLK][CELL] packed
                  int* __restrict__ cellcnt,     // [ND][NBLK]
                  int4* __restrict__ ovf,
                  int* __restrict__ ovf_count,
                  int E, int BT, int NBLK, int ND, int n8) {
    int b = blockIdx.x;
    int tid = threadIdx.x;

    if (b >= NBLK) {
        // -------- convert slice --------
        int m = (b - NBLK) * 1024 + tid;
        if (m < n8) {
            float4 a0 = support4[(size_t)m * 2];
            float4 a1 = support4[(size_t)m * 2 + 1];
            half8v h;
            h[0] = (_Float16)a0.x; h[1] = (_Float16)a0.y;
            h[2] = (_Float16)a0.z; h[3] = (_Float16)a0.w;
            h[4] = (_Float16)a1.x; h[5] = (_Float16)a1.y;
            h[6] = (_Float16)a1.z; h[7] = (_Float16)a1.w;
            supporth[m] = h;
        }
        return;
    }

    // -------- bin slice --------
    __shared__ int hist[512];
    for (int i = tid; i < 512; i += 1024) hist[i] = 0;
    __syncthreads();

    int t = b * 1024 + tid;
    int   r[EPT];
    int   c[EPT];
    float v[EPT];
    int   rk[EPT];

    #pragma unroll
    for (int i = 0; i < EPT; ++i) {
        int e = t + i * BT;
        r[i] = (e < E) ? rows[e] : -1;
    }
    #pragma unroll
    for (int i = 0; i < EPT; ++i) {
        int e = t + i * BT;
        if (e < E) { c[i] = cols[e]; v[i] = vals[e]; }
    }
    // LDS return-atomics: ~30 cyc, not a far-atomic round trip
    #pragma unroll
    for (int i = 0; i < EPT; ++i)
        rk[i] = (r[i] >= 0) ? atomicAdd(&hist[r[i] >> 8], 1) : 0;

    #pragma unroll
    for (int i = 0; i < EPT; ++i) {
        if (r[i] < 0) continue;
        int d = r[i] >> 8;
        if (rk[i] < CELL) {
            int2 q;
            q.x = ((r[i] & 255) << 17) | c[i];   // c < 2^17, r&255 in bits 17..24
            q.y = __float_as_int(v[i]);
            coarse[((size_t)d * NBLK + b) * CELL + rk[i]] = q;
        } else {
            int o = atomicAdd(ovf_count, 1);  // far, rare (~1e3 edges)
            if (o < OVF_CAP) {
                int4 q;
                q.x = r[i]; q.y = c[i]; q.z = __float_as_int(v[i]); q.w = 0;
                ovf[o] = q;
            }
        }
    }
    __syncthreads();
    for (int d = tid; d < ND; d += 1024) {
        int h = hist[d];
        cellcnt[(size_t)d * NBLK + b] = (h < CELL) ? h : CELL;
    }
}

// ====== bucket gather: consume coarse cells directly, accumulate in LDS ======
// grid = ND*2 blocks: blockIdx>>1 = 256-row bucket d, blockIdx&1 = feature half.
// 1024 threads = 64 groups of 16 lanes; each group processes one cell entry,
// each lane covers 4 consecutive feats (half4 fp16 read = 8B, coalesced 128B/edge).

__global__ __launch_bounds__(1024, 8) void
bucket_gather_kernel(const half4v* __restrict__ supporth,
                     const int2* __restrict__ coarse,
                     const int* __restrict__ cellcnt,
                     float4* __restrict__ out4,
                     int NBLK, int N) {
    __shared__ float accum[256][64];   // 64 KB; rotate-swizzled cols
    const int d   = blockIdx.x >> 1;
    const int h   = blockIdx.x & 1;
    const int tid = threadIdx.x;

    float* af = &accum[0][0];
    for (int s = tid; s < 256 * 64; s += 1024) af[s] = 0.f;
    __syncthreads();

    const int i  = tid & 15;
    const int i4 = i << 2;
    const int g  = tid >> 4;
    const int2* cbase = coarse  + (size_t)d * NBLK * CELL;
    const int*  ccnt  = cellcnt + (size_t)d * NBLK;
    const int total = NBLK * CELL;

    for (int s0 = g; s0 < total; s0 += 64 * GU) {
        int    rl[GU];
        float  va[GU];
        half4v sv[GU];
        bool   ok[GU];
        #pragma unroll
        for (int u = 0; u < GU; ++u) {
            int s = s0 + u * 64;
            ok[u] = false;
            rl[u] = 0;
            va[u] = 0.f;
            if (s < total && (s & (CELL - 1)) < ccnt[s >> 5]) {   // CELL == 32
                int2 q = cbase[s];
                rl[u] = (q.x >> 17) & 255;
                int c = q.x & 0x1FFFF;
                va[u] = __int_as_float(q.y);
                sv[u] = supporth[(size_t)c * H4 + (h << 4) + i];
                ok[u] = true;
            }
        }
        #pragma unroll
        for (int u = 0; u < GU; ++u) {
            if (ok[u]) {
                int r = rl[u];
                float v = va[u];
                // rotate swizzle: spreads the wave's 4 groups across bank classes
                atomicAdd(&accum[r][(i4 + 0 + r) & 63], v * (float)sv[u][0]);
                atomicAdd(&accum[r][(i4 + 1 + r) & 63], v * (float)sv[u][1]);
                atomicAdd(&accum[r][(i4 + 2 + r) & 63], v * (float)sv[u][2]);
                atomicAdd(&accum[r][(i4 + 3 + r) & 63], v * (float)sv[u][3]);
            }
        }
    }
    __syncthreads();

    int base = d << 8;
    int nr = N - base;
    if (nr > 256) nr = 256;
    if (nr < 0) nr = 0;
    for (int s = tid; s < nr * 16; s += 1024) {
        int r  = s >> 4;
        int jj = (s & 15) << 2;
        vfloat4 w;
        w.x = accum[r][(jj + 0 + r) & 63];
        w.y = accum[r][(jj + 1 + r) & 63];
        w.z = accum[r][(jj + 2 + r) & 63];
        w.w = accum[r][(jj + 3 + r) & 63];
        __builtin_nontemporal_store(
            w, (vfloat4*)&out4[(size_t)(base + r) * F4 + (h << 4) + (s & 15)]);
    }
}

// ============ overflow cleanup (after gather; adds onto its output) ============

__global__ void ovf_scatter_kernel(const float* __restrict__ support,
                                   const int4* __restrict__ ovf,
                                   const int* __restrict__ ovf_count,
                                   float* __restrict__ out, int cap) {
    int gid = blockIdx.x * blockDim.x + threadIdx.x;
    int i = gid >> 5;
    int j = gid & 31;
    int istride = (gridDim.x * blockDim.x) >> 5;
    int cnt = *ovf_count;
    if (cnt > cap) cnt = cap;
    for (; i < cnt; i += istride) {
        int4 q = ovf[i];
        float v = __int_as_float(q.z);
        const float4* s4 = (const float4*)support + (size_t)q.y * F4 + j;
        float4 s = *s4;
        float* o = out + (size_t)q.x * D_FEAT + j * 4;
        unsafeAtomicAdd(o + 0, v * s.x);
        unsafeAtomicAdd(o + 1, v * s.y);
        unsafeAtomicAdd(o + 2, v * s.z);
        unsafeAtomicAdd(o + 3, v * s.w);
    }
}

// ================= fallback 1: R5 fp16 path (device return-atomics) =================

__global__ void convert_kernel(const float4* __restrict__ in,
                               half8v* __restrict__ out, int n8) {
    int t = blockIdx.x * blockDim.x + threadIdx.x;
    if (t >= n8) return;
    float4 a = in[(size_t)t * 2];
    float4 b = in[(size_t)t * 2 + 1];
    half8v h;
    h[0] = (_Float16)a.x; h[1] = (_Float16)a.y;
    h[2] = (_Float16)a.z; h[3] = (_Float16)a.w;
    h[4] = (_Float16)b.x; h[5] = (_Float16)b.y;
    h[6] = (_Float16)b.z; h[7] = (_Float16)b.w;
    out[t] = h;
}

__global__ void gather_half_kernel(const half4v* __restrict__ supporth,
                                   const int* __restrict__ cursor,
                                   const int2* __restrict__ pairs,
                                   float4* __restrict__ out4, int n_nodes) {
    unsigned int t = blockIdx.x * blockDim.x + threadIdx.x;
    unsigned int row = t >> 5;
    unsigned int j = t & 31;
    if (row >= (unsigned int)n_nodes) return;
    int deg = cursor[row];
    if (deg > STRIDE) deg = STRIDE;
    const int2* pr = pairs + (size_t)row * STRIDE;
    int2 z = {0, 0};
    int2 p0 = ((int)j < deg) ? pr[j] : z;
    int2 p1 = ((int)(j + 32) < deg) ? pr[j + 32] : z;
    int   c0 = p0.x;  float v0 = __int_as_float(p0.y);
    int   c1 = p1.x;  float v1 = __int_as_float(p1.y);
    int degr = (deg + 7) & ~7;
    float4 acc[4];
    #pragma unroll
    for (int u = 0; u < 4; ++u) acc[u] = {0.f, 0.f, 0.f, 0.f};
    for (int k = 0; k < degr; k += 8) {
        int   cc[8];
        float vv[8];
        #pragma unroll
        for (int u = 0; u < 8; ++u) {
            int kk = k + u;
            cc[u] = __shfl(kk < 32 ? c0 : c1, kk & 31, 32);
            vv[u] = __shfl(kk < 32 ? v0 : v1, kk & 31, 32);
        }
        half4v s[8];
        #pragma unroll
        for (int u = 0; u < 8; ++u)
            s[u] = supporth[(size_t)cc[u] * H4 + j];
        #pragma unroll
        for (int u = 0; u < 8; ++u) {
            acc[u & 3].x += vv[u] * (float)s[u][0];
            acc[u & 3].y += vv[u] * (float)s[u][1];
            acc[u & 3].z += vv[u] * (float)s[u][2];
            acc[u & 3].w += vv[u] * (float)s[u][3];
        }
    }
    vfloat4 res;
    res.x = (acc[0].x + acc[1].x) + (acc[2].x + acc[3].x);
    res.y = (acc[0].y + acc[1].y) + (acc[2].y + acc[3].y);
    res.z = (acc[0].z + acc[1].z) + (acc[2].z + acc[3].z);
    res.w = (acc[0].w + acc[1].w) + (acc[2].w + acc[3].w);
    __builtin_nontemporal_store(res, (vfloat4*)&out4[(size_t)row * F4 + j]);
}

__global__ void bucket_ilp_kernel(const int* __restrict__ rows,
                                  const int* __restrict__ cols,
                                  const float* __restrict__ vals,
                                  int* __restrict__ cursor,
                                  int* __restrict__ ovf_count,
                                  int2* __restrict__ pairs,
                                  int4* __restrict__ ovf,
                                  int n_edges, int gstride) {
    int tid = blockIdx.x * blockDim.x + threadIdx.x;
    int   r[EPT];
    int   c[EPT];
    float v[EPT];
    int   slot[EPT];
    #pragma unroll
    for (int i = 0; i < EPT; ++i) {
        int e = tid + i * gstride;
        r[i] = (e < n_edges) ? rows[e] : -1;
    }
    #pragma unroll
    for (int i = 0; i < EPT; ++i) {
        int e = tid + i * gstride;
        if (e < n_edges) { c[i] = cols[e]; v[i] = vals[e]; }
    }
    #pragma unroll
    for (int i = 0; i < EPT; ++i)
        slot[i] = (r[i] >= 0) ? atomicAdd(&cursor[r[i]], 1) : 0;
    #pragma unroll
    for (int i = 0; i < EPT; ++i) {
        if (r[i] < 0) continue;
        int2 p;
        p.x = c[i];
        p.y = __float_as_int(v[i]);
        if (slot[i] < STRIDE) {
            pairs[(size_t)r[i] * STRIDE + slot[i]] = p;
        } else {
            int o = atomicAdd(ovf_count, 1);
            if (o < OVF_CAP) {
                int4 q; q.x = r[i]; q.y = p.x; q.z = p.y; q.w = 0;
                ovf[o] = q;
            }
        }
    }
}

// ==================== fallback 2: atomic scatter (R0) ====================

__global__ void gc_scatter_kernel(const float* __restrict__ support,
                                  const float* __restrict__ vals,
                                  const int* __restrict__ rows,
                                  const int* __restrict__ cols,
                                  float* __restrict__ out, int n_edges) {
    unsigned int t = blockIdx.x * blockDim.x + threadIdx.x;
    unsigned int e = t >> 5;
    unsigned int j = t & 31;
    if (e >= (unsigned int)n_edges) return;
    int r = rows[e];
    int c = cols[e];
    float v = vals[e];
    const float4* s4 = reinterpret_cast<const float4*>(support) + (size_t)c * F4 + j;
    float4 s = *s4;
    float* o = out + (size_t)r * D_FEAT + j * 4;
    unsafeAtomicAdd(o + 0, v * s.x);
    unsafeAtomicAdd(o + 1, v * s.y);
    unsafeAtomicAdd(o + 2, v * s.z);
    unsafeAtomicAdd(o + 3, v * s.w);
}

// ============================ launch ============================

extern "C" void kernel_launch(void* const* d_in, const int* in_sizes, int n_in,
                              void* d_out, int out_size, void* d_ws, size_t ws_size,
                              hipStream_t stream) {
    const float* support = (const float*)d_in[0];
    const float* vals    = (const float*)d_in[1];
    const int*   rows    = (const int*)d_in[2];
    const int*   cols    = (const int*)d_in[3];
    float* out = (float*)d_out;

    int E = in_sizes[1];
    int N = in_sizes[0] / D_FEAT;
    int n8 = N * D_FEAT / 8;
    int ND = (N + 255) >> 8;                      // coarse buckets (391)
    int NBLK = (E + 1024 * EPT - 1) / (1024 * EPT);  // phase-1 bin blocks (196)
    int BT = NBLK * 1024;

    char* ws = (char*)d_ws;
    size_t cur = 0;
    auto carve = [&](size_t bytes) -> void* {
        void* p = ws + cur;
        cur += (bytes + 255) & ~(size_t)255;
        return p;
    };

    // ---- primary: LDS-ranked binning + per-bucket LDS-accumulating gather ----
    {
        size_t save = cur;
        int2*   coarse    = (int2*)carve((size_t)ND * NBLK * CELL * 8);
        int*    cellcnt   = (int*)carve((size_t)ND * NBLK * 4);
        int4*   ovf       = (int4*)carve((size_t)OVF_CAP * 16);
        int*    ovf_count = (int*)carve(256);
        half8v* supporth  = (half8v*)carve((size_t)N * D_FEAT * 2);
        if (cur <= ws_size && ND <= 512) {
            (void)hipMemsetAsync(ovf_count, 0, 4, stream);
            int cblocks = (n8 + 1023) / 1024;
            phase1_bin_kernel<<<NBLK + cblocks, 1024, 0, stream>>>(
                (const float4*)support, supporth, rows, cols, vals,
                coarse, cellcnt, ovf, ovf_count, E, BT, NBLK, ND, n8);
            bucket_gather_kernel<<<ND * 2, 1024, 0, stream>>>(
                (const half4v*)supporth, coarse, cellcnt, (float4*)out, NBLK, N);
            ovf_scatter_kernel<<<512, 256, 0, stream>>>(
                support, ovf, ovf_count, out, OVF_CAP);
            return;
        }
        cur = save;
    }

    // ---- fallback 1: R5 fp16 padded buckets (device return-atomics) ----
    {
        size_t save = cur;
        int*    cursor   = (int*)carve((size_t)(N + 1) * 4);
        int2*   pairs    = (int2*)carve((size_t)N * STRIDE * 8);
        int4*   ovf      = (int4*)carve((size_t)8192 * 16);
        half8v* supporth = (half8v*)carve((size_t)N * D_FEAT * 2);
        if (cur <= ws_size) {
            int* ovf_count = cursor + N;
            int bthreads = (E + EPT - 1) / EPT;
            int bblocks = (bthreads + 255) / 256;
            int gstride = bblocks * 256;
            (void)hipMemsetAsync(cursor, 0, (size_t)(N + 1) * 4, stream);
            convert_kernel<<<(n8 + 255) / 256, 256, 0, stream>>>(
                (const float4*)support, supporth, n8);
            bucket_ilp_kernel<<<bblocks, 256, 0, stream>>>(
                rows, cols, vals, cursor, ovf_count, pairs, ovf, E, gstride);
            unsigned int gthreads = (unsigned int)N * 32;
            gather_half_kernel<<<(gthreads + 255) / 256, 256, 0, stream>>>(
                (const half4v*)supporth, cursor, pairs, (float4*)out, N);
            ovf_scatter_kernel<<<512, 256, 0, stream>>>(
                support, ovf, ovf_count, out, 8192);
            return;
        }
        cur = save;
    }

    // ---- fallback 2: atomic scatter ----
    (void)hipMemsetAsync(d_out, 0, (size_t)out_size * sizeof(float), stream);
    unsigned int total = (unsigned int)E * 32;
    gc_scatter_kernel<<<(total + 255) / 256, 256, 0, stream>>>(
        support, vals, rows, cols, out, E);
}

// Round 2
// 1475.259 us; speedup vs baseline: 1.0025x; 1.0025x over previous
//
#include <hip/hip_runtime.h>
#include <hip/hip_bf16.h>
#include <hip/hip_fp16.h>

// GraphConvolution: out = segment_sum(vals[:,None] * support[cols], rows)
// N=100000 nodes, E=1600000 edges, F=128 features, fp32.
//
// Round 9: R8 post-mortem — bucket_gather was 1366us with ALL pipes idle
//  (HBM 2%, VALU 3.9%, conflicts negligible). Diagnosis: plain atomicAdd on
//  __shared__ float compiles to a ds_read/ds_cmpst CAS RETRY LOOP (no
//  unsafe-fp-atomics), i.e. 12.8M serialized LDS round-trips with contention
//  spin. Fix: unsafeAtomicAdd -> native fire-and-forget ds_add_f32
//  (addrspace(3) statically known). DS-pipe floor ~31us/CU, hidden under
//  ~170MB random VMEM. Everything else unchanged from R8.

#define D_FEAT 128
#define F4 32            // float4s per feature vector
#define H4 32            // half4s per feature vector
#define STRIDE 64        // padded slots per row (fallback 1 only)
#define CELL 32          // slots per (bucket, block) cell (Poisson(21))
#define OVF_CAP 131072   // overflow list capacity
#define EPT 8            // edges per thread in phase 1
#define GU 4             // entries per group-iteration in bucket_gather

typedef float    vfloat4 __attribute__((ext_vector_type(4)));
typedef _Float16 half4v  __attribute__((ext_vector_type(4)));
typedef _Float16 half8v  __attribute__((ext_vector_type(8)));

// ============ phase 1: coarse bin (LDS ranks) + fused fp32->fp16 convert ============

__global__ __launch_bounds__(1024) void
phase1_bin_kernel(const float4* __restrict__ support4,
                  half8v* __restrict__ supporth,
                  const int* __restrict__ rows,
                  const int* __restrict__ cols,
                  const float* __restrict__ vals,
                  int2* __restrict__ coarse,     // [ND][NBLK][CELL] packed
                  int* __restrict__ cellcnt,     // [ND][NBLK]
                  int4* __restrict__ ovf,
                  int* __restrict__ ovf_count,
                  int E, int BT, int NBLK, int ND, int n8) {
    int b = blockIdx.x;
    int tid = threadIdx.x;

    if (b >= NBLK) {
        // -------- convert slice --------
        int m = (b - NBLK) * 1024 + tid;
        if (m < n8) {
            float4 a0 = support4[(size_t)m * 2];
            float4 a1 = support4[(size_t)m * 2 + 1];
            half8v h;
            h[0] = (_Float16)a0.x; h[1] = (_Float16)a0.y;
            h[2] = (_Float16)a0.z; h[3] = (_Float16)a0.w;
            h[4] = (_Float16)a1.x; h[5] = (_Float16)a1.y;
            h[6] = (_Float16)a1.z; h[7] = (_Float16)a1.w;
            supporth[m] = h;
        }
        return;
    }

    // -------- bin slice --------
    __shared__ int hist[512];
    for (int i = tid; i < 512; i += 1024) hist[i] = 0;
    __syncthreads();

    int t = b * 1024 + tid;
    int   r[EPT];
    int   c[EPT];
    float v[EPT];
    int   rk[EPT];

    #pragma unroll
    for (int i = 0; i < EPT; ++i) {
        int e = t + i * BT;
        r[i] = (e < E) ? rows[e] : -1;
    }
    #pragma unroll
    for (int i = 0; i < EPT; ++i) {
        int e = t + i * BT;
        if (e < E) { c[i] = cols[e]; v[i] = vals[e]; }
    }
    // LDS int return-atomics: native ds_add_rtn_u32, ~30 cyc
    #pragma unroll
    for (int i = 0; i < EPT; ++i)
        rk[i] = (r[i] >= 0) ? atomicAdd(&hist[r[i] >> 8], 1) : 0;

    #pragma unroll
    for (int i = 0; i < EPT; ++i) {
        if (r[i] < 0) continue;
        int d = r[i] >> 8;
        if (rk[i] < CELL) {
            int2 q;
            q.x = ((r[i] & 255) << 17) | c[i];   // c < 2^17, r&255 in bits 17..24
            q.y = __float_as_int(v[i]);
            coarse[((size_t)d * NBLK + b) * CELL + rk[i]] = q;
        } else {
            int o = atomicAdd(ovf_count, 1);  // far, rare (~1e3 edges)
            if (o < OVF_CAP) {
                int4 q;
                q.x = r[i]; q.y = c[i]; q.z = __float_as_int(v[i]); q.w = 0;
                ovf[o] = q;
            }
        }
    }
    __syncthreads();
    for (int d = tid; d < ND; d += 1024) {
        int h = hist[d];
        cellcnt[(size_t)d * NBLK + b] = (h < CELL) ? h : CELL;
    }
}

// ====== bucket gather: consume coarse cells directly, accumulate in LDS ======
// grid = ND*2 blocks: blockIdx>>1 = 256-row bucket d, blockIdx&1 = feature half.
// 1024 threads = 64 groups of 16 lanes; each group processes one cell entry,
// each lane covers 4 consecutive feats (half4 fp16 read = 8B, coalesced 128B/edge).

__global__ __launch_bounds__(1024, 8) void
bucket_gather_kernel(const half4v* __restrict__ supporth,
                     const int2* __restrict__ coarse,
                     const int* __restrict__ cellcnt,
                     float4* __restrict__ out4,
                     int NBLK, int N) {
    __shared__ float accum[256][64];   // 64 KB; rotate-swizzled cols
    const int d   = blockIdx.x >> 1;
    const int h   = blockIdx.x & 1;
    const int tid = threadIdx.x;

    float* af = &accum[0][0];
    for (int s = tid; s < 256 * 64; s += 1024) af[s] = 0.f;
    __syncthreads();

    const int i  = tid & 15;
    const int i4 = i << 2;
    const int g  = tid >> 4;
    const int2* cbase = coarse  + (size_t)d * NBLK * CELL;
    const int*  ccnt  = cellcnt + (size_t)d * NBLK;
    const int total = NBLK * CELL;

    for (int s0 = g; s0 < total; s0 += 64 * GU) {
        int    rl[GU];
        float  va[GU];
        half4v sv[GU];
        bool   ok[GU];
        #pragma unroll
        for (int u = 0; u < GU; ++u) {
            int s = s0 + u * 64;
            ok[u] = false;
            rl[u] = 0;
            va[u] = 0.f;
            if (s < total && (s & (CELL - 1)) < ccnt[s >> 5]) {   // CELL == 32
                int2 q = cbase[s];
                rl[u] = (q.x >> 17) & 255;
                int c = q.x & 0x1FFFF;
                va[u] = __int_as_float(q.y);
                sv[u] = supporth[(size_t)c * H4 + (h << 4) + i];
                ok[u] = true;
            }
        }
        #pragma unroll
        for (int u = 0; u < GU; ++u) {
            if (ok[u]) {
                int r = rl[u];
                float v = va[u];
                // rotate swizzle spreads groups across bank classes;
                // unsafeAtomicAdd -> native fire-and-forget ds_add_f32
                // (plain atomicAdd = CAS retry loop = R8's 1366us disaster)
                unsafeAtomicAdd(&accum[r][(i4 + 0 + r) & 63], v * (float)sv[u][0]);
                unsafeAtomicAdd(&accum[r][(i4 + 1 + r) & 63], v * (float)sv[u][1]);
                unsafeAtomicAdd(&accum[r][(i4 + 2 + r) & 63], v * (float)sv[u][2]);
                unsafeAtomicAdd(&accum[r][(i4 + 3 + r) & 63], v * (float)sv[u][3]);
            }
        }
    }
    __syncthreads();

    int base = d << 8;
    int nr = N - base;
    if (nr > 256) nr = 256;
    if (nr < 0) nr = 0;
    for (int s = tid; s < nr * 16; s += 1024) {
        int r  = s >> 4;
        int jj = (s & 15) << 2;
        vfloat4 w;
        w.x = accum[r][(jj + 0 + r) & 63];
        w.y = accum[r][(jj + 1 + r) & 63];
        w.z = accum[r][(jj + 2 + r) & 63];
        w.w = accum[r][(jj + 3 + r) & 63];
        __builtin_nontemporal_store(
            w, (vfloat4*)&out4[(size_t)(base + r) * F4 + (h << 4) + (s & 15)]);
    }
}

// ============ overflow cleanup (after gather; adds onto its output) ============

__global__ void ovf_scatter_kernel(const float* __restrict__ support,
                                   const int4* __restrict__ ovf,
                                   const int* __restrict__ ovf_count,
                                   float* __restrict__ out, int cap) {
    int gid = blockIdx.x * blockDim.x + threadIdx.x;
    int i = gid >> 5;
    int j = gid & 31;
    int istride = (gridDim.x * blockDim.x) >> 5;
    int cnt = *ovf_count;
    if (cnt > cap) cnt = cap;
    for (; i < cnt; i += istride) {
        int4 q = ovf[i];
        float v = __int_as_float(q.z);
        const float4* s4 = (const float4*)support + (size_t)q.y * F4 + j;
        float4 s = *s4;
        float* o = out + (size_t)q.x * D_FEAT + j * 4;
        unsafeAtomicAdd(o + 0, v * s.x);
        unsafeAtomicAdd(o + 1, v * s.y);
        unsafeAtomicAdd(o + 2, v * s.z);
        unsafeAtomicAdd(o + 3, v * s.w);
    }
}

// ================= fallback 1: R5 fp16 path (device return-atomics) =================

__global__ void convert_kernel(const float4* __restrict__ in,
                               half8v* __restrict__ out, int n8) {
    int t = blockIdx.x * blockDim.x + threadIdx.x;
    if (t >= n8) return;
    float4 a = in[(size_t)t * 2];
    float4 b = in[(size_t)t * 2 + 1];
    half8v h;
    h[0] = (_Float16)a.x; h[1] = (_Float16)a.y;
    h[2] = (_Float16)a.z; h[3] = (_Float16)a.w;
    h[4] = (_Float16)b.x; h[5] = (_Float16)b.y;
    h[6] = (_Float16)b.z; h[7] = (_Float16)b.w;
    out[t] = h;
}

__global__ void gather_half_kernel(const half4v* __restrict__ supporth,
                                   const int* __restrict__ cursor,
                                   const int2* __restrict__ pairs,
                                   float4* __restrict__ out4, int n_nodes) {
    unsigned int t = blockIdx.x * blockDim.x + threadIdx.x;
    unsigned int row = t >> 5;
    unsigned int j = t & 31;
    if (row >= (unsigned int)n_nodes) return;
    int deg = cursor[row];
    if (deg > STRIDE) deg = STRIDE;
    const int2* pr = pairs + (size_t)row * STRIDE;
    int2 z = {0, 0};
    int2 p0 = ((int)j < deg) ? pr[j] : z;
    int2 p1 = ((int)(j + 32) < deg) ? pr[j + 32] : z;
    int   c0 = p0.x;  float v0 = __int_as_float(p0.y);
    int   c1 = p1.x;  float v1 = __int_as_float(p1.y);
    int degr = (deg + 7) & ~7;
    float4 acc[4];
    #pragma unroll
    for (int u = 0; u < 4; ++u) acc[u] = {0.f, 0.f, 0.f, 0.f};
    for (int k = 0; k < degr; k += 8) {
        int   cc[8];
        float vv[8];
        #pragma unroll
        for (int u = 0; u < 8; ++u) {
            int kk = k + u;
            cc[u] = __shfl(kk < 32 ? c0 : c1, kk & 31, 32);
            vv[u] = __shfl(kk < 32 ? v0 : v1, kk & 31, 32);
        }
        half4v s[8];
        #pragma unroll
        for (int u = 0; u < 8; ++u)
            s[u] = supporth[(size_t)cc[u] * H4 + j];
        #pragma unroll
        for (int u = 0; u < 8; ++u) {
            acc[u & 3].x += vv[u] * (float)s[u][0];
            acc[u & 3].y += vv[u] * (float)s[u][1];
            acc[u & 3].z += vv[u] * (float)s[u][2];
            acc[u & 3].w += vv[u] * (float)s[u][3];
        }
    }
    vfloat4 res;
    res.x = (acc[0].x + acc[1].x) + (acc[2].x + acc[3].x);
    res.y = (acc[0].y + acc[1].y) + (acc[2].y + acc[3].y);
    res.z = (acc[0].z + acc[1].z) + (acc[2].z + acc[3].z);
    res.w = (acc[0].w + acc[1].w) + (acc[2].w + acc[3].w);
    __builtin_nontemporal_store(res, (vfloat4*)&out4[(size_t)row * F4 + j]);
}

__global__ void bucket_ilp_kernel(const int* __restrict__ rows,
                                  const int* __restrict__ cols,
                                  const float* __restrict__ vals,
                                  int* __restrict__ cursor,
                                  int* __restrict__ ovf_count,
                                  int2* __restrict__ pairs,
                                  int4* __restrict__ ovf,
                                  int n_edges, int gstride) {
    int tid = blockIdx.x * blockDim.x + threadIdx.x;
    int   r[EPT];
    int   c[EPT];
    float v[EPT];
    int   slot[EPT];
    #pragma unroll
    for (int i = 0; i < EPT; ++i) {
        int e = tid + i * gstride;
        r[i] = (e < n_edges) ? rows[e] : -1;
    }
    #pragma unroll
    for (int i = 0; i < EPT; ++i) {
        int e = tid + i * gstride;
        if (e < n_edges) { c[i] = cols[e]; v[i] = vals[e]; }
    }
    #pragma unroll
    for (int i = 0; i < EPT; ++i)
        slot[i] = (r[i] >= 0) ? atomicAdd(&cursor[r[i]], 1) : 0;
    #pragma unroll
    for (int i = 0; i < EPT; ++i) {
        if (r[i] < 0) continue;
        int2 p;
        p.x = c[i];
        p.y = __float_as_int(v[i]);
        if (slot[i] < STRIDE) {
            pairs[(size_t)r[i] * STRIDE + slot[i]] = p;
        } else {
            int o = atomicAdd(ovf_count, 1);
            if (o < OVF_CAP) {
                int4 q; q.x = r[i]; q.y = p.x; q.z = p.y; q.w = 0;
                ovf[o] = q;
            }
        }
    }
}

// ==================== fallback 2: atomic scatter (R0) ====================

__global__ void gc_scatter_kernel(const float* __restrict__ support,
                                  const float* __restrict__ vals,
                                  const int* __restrict__ rows,
                                  const int* __restrict__ cols,
                                  float* __restrict__ out, int n_edges) {
    unsigned int t = blockIdx.x * blockDim.x + threadIdx.x;
    unsigned int e = t >> 5;
    unsigned int j = t & 31;
    if (e >= (unsigned int)n_edges) return;
    int r = rows[e];
    int c = cols[e];
    float v = vals[e];
    const float4* s4 = reinterpret_cast<const float4*>(support) + (size_t)c * F4 + j;
    float4 s = *s4;
    float* o = out + (size_t)r * D_FEAT + j * 4;
    unsafeAtomicAdd(o + 0, v * s.x);
    unsafeAtomicAdd(o + 1, v * s.y);
    unsafeAtomicAdd(o + 2, v * s.z);
    unsafeAtomicAdd(o + 3, v * s.w);
}

// ============================ launch ============================

extern "C" void kernel_launch(void* const* d_in, const int* in_sizes, int n_in,
                              void* d_out, int out_size, void* d_ws, size_t ws_size,
                              hipStream_t stream) {
    const float* support = (const float*)d_in[0];
    const float* vals    = (const float*)d_in[1];
    const int*   rows    = (const int*)d_in[2];
    const int*   cols    = (const int*)d_in[3];
    float* out = (float*)d_out;

    int E = in_sizes[1];
    int N = in_sizes[0] / D_FEAT;
    int n8 = N * D_FEAT / 8;
    int ND = (N + 255) >> 8;                      // coarse buckets (391)
    int NBLK = (E + 1024 * EPT - 1) / (1024 * EPT);  // phase-1 bin blocks (196)
    int BT = NBLK * 1024;

    char* ws = (char*)d_ws;
    size_t cur = 0;
    auto carve = [&](size_t bytes) -> void* {
        void* p = ws + cur;
        cur += (bytes + 255) & ~(size_t)255;
        return p;
    };

    // ---- primary: LDS-ranked binning + per-bucket LDS-accumulating gather ----
    {
        size_t save = cur;
        int2*   coarse    = (int2*)carve((size_t)ND * NBLK * CELL * 8);
        int*    cellcnt   = (int*)carve((size_t)ND * NBLK * 4);
        int4*   ovf       = (int4*)carve((size_t)OVF_CAP * 16);
        int*    ovf_count = (int*)carve(256);
        half8v* supporth  = (half8v*)carve((size_t)N * D_FEAT * 2);
        if (cur <= ws_size && ND <= 512) {
            (void)hipMemsetAsync(ovf_count, 0, 4, stream);
            int cblocks = (n8 + 1023) / 1024;
            phase1_bin_kernel<<<NBLK + cblocks, 1024, 0, stream>>>(
                (const float4*)support, supporth, rows, cols, vals,
                coarse, cellcnt, ovf, ovf_count, E, BT, NBLK, ND, n8);
            bucket_gather_kernel<<<ND * 2, 1024, 0, stream>>>(
                (const half4v*)supporth, coarse, cellcnt, (float4*)out, NBLK, N);
            ovf_scatter_kernel<<<512, 256, 0, stream>>>(
                support, ovf, ovf_count, out, OVF_CAP);
            return;
        }
        cur = save;
    }

    // ---- fallback 1: R5 fp16 padded buckets (device return-atomics) ----
    {
        size_t save = cur;
        int*    cursor   = (int*)carve((size_t)(N + 1) * 4);
        int2*   pairs    = (int2*)carve((size_t)N * STRIDE * 8);
        int4*   ovf      = (int4*)carve((size_t)8192 * 16);
        half8v* supporth = (half8v*)carve((size_t)N * D_FEAT * 2);
        if (cur <= ws_size) {
            int* ovf_count = cursor + N;
            int bthreads = (E + EPT - 1) / EPT;
            int bblocks = (bthreads + 255) / 256;
            int gstride = bblocks * 256;
            (void)hipMemsetAsync(cursor, 0, (size_t)(N + 1) * 4, stream);
            convert_kernel<<<(n8 + 255) / 256, 256, 0, stream>>>(
                (const float4*)support, supporth, n8);
            bucket_ilp_kernel<<<bblocks, 256, 0, stream>>>(
                rows, cols, vals, cursor, ovf_count, pairs, ovf, E, gstride);
            unsigned int gthreads = (unsigned int)N * 32;
            gather_half_kernel<<<(gthreads + 255) / 256, 256, 0, stream>>>(
                (const half4v*)supporth, cursor, pairs, (float4*)out, N);
            ovf_scatter_kernel<<<512, 256, 0, stream>>>(
                support, ovf, ovf_count, out, 8192);
            return;
        }
        cur = save;
    }

    // ---- fallback 2: atomic scatter ----
    (void)hipMemsetAsync(d_out, 0, (size_t)out_size * sizeof(float), stream);
    unsigned int total = (unsigned int)E * 32;
    gc_scatter_kernel<<<(total + 255) / 256, 256, 0, stream>>>(
        support, vals, rows, cols, out, E);
}

// Round 3
// 202.151 us; speedup vs baseline: 7.3163x; 7.2978x over previous
//
#include <hip/hip_runtime.h>
#include <hip/hip_bf16.h>
#include <hip/hip_fp16.h>

// GraphConvolution: out = segment_sum(vals[:,None] * support[cols], rows)
// N=100000 nodes, E=1600000 edges, F=128 features, fp32.
//
// Round 10: R8/R9 post-mortem — bucket_gather (LDS fp-accum) stuck at 1362us
//  with ALL pipes idle regardless of atomic flavor; undiagnosable from
//  counters. Revert to R7's proven components and fuse differently:
//  bucket_csr_gather = phase2's proven ranking (per-lane coalesced coarse
//  reads + LDS int atomics) + LDS prefix-scan -> LDS-resident CSR (66KB)
//  + R7's proven 8-deep-ILP gather reading (col,val) via LDS broadcast.
//  Deletes pairs HBM round-trip (25.6MB W + 12.8MB R), cursor, one launch.
//  No LDS fp atomics, no group-uniform gated loads, no forced launch bounds.

#define D_FEAT 128
#define F4 32            // float4s per feature vector
#define H4 32            // half4s per feature vector
#define STRIDE 64        // padded slots per row (fallback 1 only)
#define CELL 32          // slots per (bucket, block) cell (Poisson(21))
#define OVF_CAP 131072   // overflow list capacity
#define EPT 8            // edges per thread in phase 1
#define MAXIT 8          // stage-1 iterations: supports NBLK*CELL <= 8192
#define MAXSLOT 8192     // LDS csr capacity (entries)

typedef float    vfloat4 __attribute__((ext_vector_type(4)));
typedef _Float16 half4v  __attribute__((ext_vector_type(4)));
typedef _Float16 half8v  __attribute__((ext_vector_type(8)));

// ============ phase 1: coarse bin (LDS ranks) + fused fp32->fp16 convert ============

__global__ __launch_bounds__(1024) void
phase1_bin_kernel(const float4* __restrict__ support4,
                  half8v* __restrict__ supporth,
                  const int* __restrict__ rows,
                  const int* __restrict__ cols,
                  const float* __restrict__ vals,
                  int2* __restrict__ coarse,     // [ND][NBLK][CELL] packed
                  int* __restrict__ cellcnt,     // [ND][NBLK]
                  int4* __restrict__ ovf,
                  int* __restrict__ ovf_count,
                  int E, int BT, int NBLK, int ND, int n8) {
    int b = blockIdx.x;
    int tid = threadIdx.x;

    if (b >= NBLK) {
        // -------- convert slice --------
        int m = (b - NBLK) * 1024 + tid;
        if (m < n8) {
            float4 a0 = support4[(size_t)m * 2];
            float4 a1 = support4[(size_t)m * 2 + 1];
            half8v h;
            h[0] = (_Float16)a0.x; h[1] = (_Float16)a0.y;
            h[2] = (_Float16)a0.z; h[3] = (_Float16)a0.w;
            h[4] = (_Float16)a1.x; h[5] = (_Float16)a1.y;
            h[6] = (_Float16)a1.z; h[7] = (_Float16)a1.w;
            supporth[m] = h;
        }
        return;
    }

    // -------- bin slice --------
    __shared__ int hist[512];
    for (int i = tid; i < 512; i += 1024) hist[i] = 0;
    __syncthreads();

    int t = b * 1024 + tid;
    int   r[EPT];
    int   c[EPT];
    float v[EPT];
    int   rk[EPT];

    #pragma unroll
    for (int i = 0; i < EPT; ++i) {
        int e = t + i * BT;
        r[i] = (e < E) ? rows[e] : -1;
    }
    #pragma unroll
    for (int i = 0; i < EPT; ++i) {
        int e = t + i * BT;
        if (e < E) { c[i] = cols[e]; v[i] = vals[e]; }
    }
    // LDS int return-atomics: native ds_add_rtn_u32, ~30 cyc
    #pragma unroll
    for (int i = 0; i < EPT; ++i)
        rk[i] = (r[i] >= 0) ? atomicAdd(&hist[r[i] >> 8], 1) : 0;

    #pragma unroll
    for (int i = 0; i < EPT; ++i) {
        if (r[i] < 0) continue;
        int d = r[i] >> 8;
        if (rk[i] < CELL) {
            int2 q;
            q.x = ((r[i] & 255) << 17) | c[i];   // c < 2^17, r&255 in bits 17..24
            q.y = __float_as_int(v[i]);
            coarse[((size_t)d * NBLK + b) * CELL + rk[i]] = q;
        } else {
            int o = atomicAdd(ovf_count, 1);  // far, rare (~1e3 edges)
            if (o < OVF_CAP) {
                int4 q;
                q.x = r[i]; q.y = c[i]; q.z = __float_as_int(v[i]); q.w = 0;
                ovf[o] = q;
            }
        }
    }
    __syncthreads();
    for (int d = tid; d < ND; d += 1024) {
        int h = hist[d];
        cellcnt[(size_t)d * NBLK + b] = (h < CELL) ? h : CELL;
    }
}

// ====== fused bucket CSR gather: phase2's ranking + R7's gather, CSR in LDS ======
// One block per 256-row bucket d. 1024 threads.
//  S1: per-lane coalesced read of bucket's coarse cells, LDS int atomic rank.
//  S2: 64-lane shuffle prefix-scan of cnt[256] -> off[257].
//  S3: scatter (col,val) entries into LDS csr[off[r]+rank].
//  S4: 32 groups x 32 lanes; group handles 8 rows; per row read (col,val)
//      by LDS broadcast, 8 independent supporth loads per lane (R7 pattern),
//      accumulate fp32, coalesced nontemporal float4 store.

__global__ __launch_bounds__(1024) void
bucket_csr_gather_kernel(const half4v* __restrict__ supporth,
                         const int2* __restrict__ coarse,
                         const int* __restrict__ cellcnt,
                         float4* __restrict__ out4,
                         int NBLK, int N) {
    __shared__ int  cnt[257];
    __shared__ int  off[257];
    __shared__ int2 csr[MAXSLOT + 8];   // +8 pad: gather reads up to end-1+7

    const int d   = blockIdx.x;
    const int tid = threadIdx.x;
    const int2* cbase = coarse  + (size_t)d * NBLK * CELL;
    const int*  ccnt  = cellcnt + (size_t)d * NBLK;
    const int total = NBLK * CELL;

    if (tid < 257) cnt[tid] = 0;
    __syncthreads();

    // ---- S1: load + rank (phase2's proven per-lane pattern) ----
    int2 ent[MAXIT];
    int  err[MAXIT];
    int  ernk[MAXIT];
    #pragma unroll
    for (int it = 0; it < MAXIT; ++it) {
        int s = tid + it * 1024;
        err[it] = -1;
        if (s < total && (s & (CELL - 1)) < ccnt[s >> 5]) {   // CELL == 32
            int2 q = cbase[s];
            int r = (q.x >> 17) & 255;
            ent[it].x = q.x & 0x1FFFF;
            ent[it].y = q.y;
            err[it] = r;
            ernk[it] = atomicAdd(&cnt[r], 1);                 // LDS int rtn atomic
        }
    }
    __syncthreads();

    // ---- S2: prefix scan cnt[256] -> off (wave 0 only) ----
    if (tid < 64) {
        int4 c4 = ((int4*)cnt)[tid];
        int t0 = c4.x;
        int t1 = t0 + c4.y;
        int t2 = t1 + c4.z;
        int t3 = t2 + c4.w;
        int inc = t3;
        #pragma unroll
        for (int dd = 1; dd < 64; dd <<= 1) {
            int t = __shfl_up(inc, dd, 64);
            if (tid >= dd) inc += t;
        }
        int excl = inc - t3;
        off[tid * 4 + 0] = excl;
        off[tid * 4 + 1] = excl + t0;
        off[tid * 4 + 2] = excl + t1;
        off[tid * 4 + 3] = excl + t2;
        if (tid == 63) off[256] = inc;
    }
    __syncthreads();

    // ---- S3: scatter into LDS CSR ----
    #pragma unroll
    for (int it = 0; it < MAXIT; ++it) {
        if (err[it] >= 0)
            csr[off[err[it]] + ernk[it]] = ent[it];
    }
    __syncthreads();

    // ---- S4: gather (R7's proven 8-deep-ILP inner loop) ----
    const int grp = tid >> 5;     // 0..31
    const int j   = tid & 31;     // feature lane: half4 = feats 4j..4j+3
    const int base = d << 8;
    for (int rq = 0; rq < 8; ++rq) {
        int r   = (rq << 5) + grp;          // 0..255
        int beg = off[r];
        int end = off[r + 1];
        float4 acc[4];
        #pragma unroll
        for (int u = 0; u < 4; ++u) acc[u] = {0.f, 0.f, 0.f, 0.f};
        for (int k0 = beg; k0 < end; k0 += 8) {
            int   cc[8];
            float vv[8];
            #pragma unroll
            for (int u = 0; u < 8; ++u) {
                int2 e = csr[k0 + u];       // LDS broadcast (uniform per group)
                bool ib = (k0 + u) < end;
                cc[u] = ib ? e.x : 0;
                vv[u] = ib ? __int_as_float(e.y) : 0.f;
            }
            half4v s[8];
            #pragma unroll
            for (int u = 0; u < 8; ++u)
                s[u] = supporth[(size_t)cc[u] * H4 + j];
            #pragma unroll
            for (int u = 0; u < 8; ++u) {
                acc[u & 3].x += vv[u] * (float)s[u][0];
                acc[u & 3].y += vv[u] * (float)s[u][1];
                acc[u & 3].z += vv[u] * (float)s[u][2];
                acc[u & 3].w += vv[u] * (float)s[u][3];
            }
        }
        int row = base + r;
        if (row < N) {
            vfloat4 res;
            res.x = (acc[0].x + acc[1].x) + (acc[2].x + acc[3].x);
            res.y = (acc[0].y + acc[1].y) + (acc[2].y + acc[3].y);
            res.z = (acc[0].z + acc[1].z) + (acc[2].z + acc[3].z);
            res.w = (acc[0].w + acc[1].w) + (acc[2].w + acc[3].w);
            __builtin_nontemporal_store(res, (vfloat4*)&out4[(size_t)row * F4 + j]);
        }
    }
}

// ============ overflow cleanup (after gather; adds onto its output) ============

__global__ void ovf_scatter_kernel(const float* __restrict__ support,
                                   const int4* __restrict__ ovf,
                                   const int* __restrict__ ovf_count,
                                   float* __restrict__ out, int cap) {
    int gid = blockIdx.x * blockDim.x + threadIdx.x;
    int i = gid >> 5;
    int j = gid & 31;
    int istride = (gridDim.x * blockDim.x) >> 5;
    int cnt = *ovf_count;
    if (cnt > cap) cnt = cap;
    for (; i < cnt; i += istride) {
        int4 q = ovf[i];
        float v = __int_as_float(q.z);
        const float4* s4 = (const float4*)support + (size_t)q.y * F4 + j;
        float4 s = *s4;
        float* o = out + (size_t)q.x * D_FEAT + j * 4;
        unsafeAtomicAdd(o + 0, v * s.x);
        unsafeAtomicAdd(o + 1, v * s.y);
        unsafeAtomicAdd(o + 2, v * s.z);
        unsafeAtomicAdd(o + 3, v * s.w);
    }
}

// ================= fallback 1: R5 fp16 path (device return-atomics) =================

__global__ void convert_kernel(const float4* __restrict__ in,
                               half8v* __restrict__ out, int n8) {
    int t = blockIdx.x * blockDim.x + threadIdx.x;
    if (t >= n8) return;
    float4 a = in[(size_t)t * 2];
    float4 b = in[(size_t)t * 2 + 1];
    half8v h;
    h[0] = (_Float16)a.x; h[1] = (_Float16)a.y;
    h[2] = (_Float16)a.z; h[3] = (_Float16)a.w;
    h[4] = (_Float16)b.x; h[5] = (_Float16)b.y;
    h[6] = (_Float16)b.z; h[7] = (_Float16)b.w;
    out[t] = h;
}

__global__ void gather_half_kernel(const half4v* __restrict__ supporth,
                                   const int* __restrict__ cursor,
                                   const int2* __restrict__ pairs,
                                   float4* __restrict__ out4, int n_nodes) {
    unsigned int t = blockIdx.x * blockDim.x + threadIdx.x;
    unsigned int row = t >> 5;
    unsigned int j = t & 31;
    if (row >= (unsigned int)n_nodes) return;
    int deg = cursor[row];
    if (deg > STRIDE) deg = STRIDE;
    const int2* pr = pairs + (size_t)row * STRIDE;
    int2 z = {0, 0};
    int2 p0 = ((int)j < deg) ? pr[j] : z;
    int2 p1 = ((int)(j + 32) < deg) ? pr[j + 32] : z;
    int   c0 = p0.x;  float v0 = __int_as_float(p0.y);
    int   c1 = p1.x;  float v1 = __int_as_float(p1.y);
    int degr = (deg + 7) & ~7;
    float4 acc[4];
    #pragma unroll
    for (int u = 0; u < 4; ++u) acc[u] = {0.f, 0.f, 0.f, 0.f};
    for (int k = 0; k < degr; k += 8) {
        int   cc[8];
        float vv[8];
        #pragma unroll
        for (int u = 0; u < 8; ++u) {
            int kk = k + u;
            cc[u] = __shfl(kk < 32 ? c0 : c1, kk & 31, 32);
            vv[u] = __shfl(kk < 32 ? v0 : v1, kk & 31, 32);
        }
        half4v s[8];
        #pragma unroll
        for (int u = 0; u < 8; ++u)
            s[u] = supporth[(size_t)cc[u] * H4 + j];
        #pragma unroll
        for (int u = 0; u < 8; ++u) {
            acc[u & 3].x += vv[u] * (float)s[u][0];
            acc[u & 3].y += vv[u] * (float)s[u][1];
            acc[u & 3].z += vv[u] * (float)s[u][2];
            acc[u & 3].w += vv[u] * (float)s[u][3];
        }
    }
    vfloat4 res;
    res.x = (acc[0].x + acc[1].x) + (acc[2].x + acc[3].x);
    res.y = (acc[0].y + acc[1].y) + (acc[2].y + acc[3].y);
    res.z = (acc[0].z + acc[1].z) + (acc[2].z + acc[3].z);
    res.w = (acc[0].w + acc[1].w) + (acc[2].w + acc[3].w);
    __builtin_nontemporal_store(res, (vfloat4*)&out4[(size_t)row * F4 + j]);
}

__global__ void bucket_ilp_kernel(const int* __restrict__ rows,
                                  const int* __restrict__ cols,
                                  const float* __restrict__ vals,
                                  int* __restrict__ cursor,
                                  int* __restrict__ ovf_count,
                                  int2* __restrict__ pairs,
                                  int4* __restrict__ ovf,
                                  int n_edges, int gstride) {
    int tid = blockIdx.x * blockDim.x + threadIdx.x;
    int   r[EPT];
    int   c[EPT];
    float v[EPT];
    int   slot[EPT];
    #pragma unroll
    for (int i = 0; i < EPT; ++i) {
        int e = tid + i * gstride;
        r[i] = (e < n_edges) ? rows[e] : -1;
    }
    #pragma unroll
    for (int i = 0; i < EPT; ++i) {
        int e = tid + i * gstride;
        if (e < n_edges) { c[i] = cols[e]; v[i] = vals[e]; }
    }
    #pragma unroll
    for (int i = 0; i < EPT; ++i)
        slot[i] = (r[i] >= 0) ? atomicAdd(&cursor[r[i]], 1) : 0;
    #pragma unroll
    for (int i = 0; i < EPT; ++i) {
        if (r[i] < 0) continue;
        int2 p;
        p.x = c[i];
        p.y = __float_as_int(v[i]);
        if (slot[i] < STRIDE) {
            pairs[(size_t)r[i] * STRIDE + slot[i]] = p;
        } else {
            int o = atomicAdd(ovf_count, 1);
            if (o < OVF_CAP) {
                int4 q; q.x = r[i]; q.y = p.x; q.z = p.y; q.w = 0;
                ovf[o] = q;
            }
        }
    }
}

// ==================== fallback 2: atomic scatter (R0) ====================

__global__ void gc_scatter_kernel(const float* __restrict__ support,
                                  const float* __restrict__ vals,
                                  const int* __restrict__ rows,
                                  const int* __restrict__ cols,
                                  float* __restrict__ out, int n_edges) {
    unsigned int t = blockIdx.x * blockDim.x + threadIdx.x;
    unsigned int e = t >> 5;
    unsigned int j = t & 31;
    if (e >= (unsigned int)n_edges) return;
    int r = rows[e];
    int c = cols[e];
    float v = vals[e];
    const float4* s4 = reinterpret_cast<const float4*>(support) + (size_t)c * F4 + j;
    float4 s = *s4;
    float* o = out + (size_t)r * D_FEAT + j * 4;
    unsafeAtomicAdd(o + 0, v * s.x);
    unsafeAtomicAdd(o + 1, v * s.y);
    unsafeAtomicAdd(o + 2, v * s.z);
    unsafeAtomicAdd(o + 3, v * s.w);
}

// ============================ launch ============================

extern "C" void kernel_launch(void* const* d_in, const int* in_sizes, int n_in,
                              void* d_out, int out_size, void* d_ws, size_t ws_size,
                              hipStream_t stream) {
    const float* support = (const float*)d_in[0];
    const float* vals    = (const float*)d_in[1];
    const int*   rows    = (const int*)d_in[2];
    const int*   cols    = (const int*)d_in[3];
    float* out = (float*)d_out;

    int E = in_sizes[1];
    int N = in_sizes[0] / D_FEAT;
    int n8 = N * D_FEAT / 8;
    int ND = (N + 255) >> 8;                      // coarse buckets (391)
    int NBLK = (E + 1024 * EPT - 1) / (1024 * EPT);  // phase-1 bin blocks (196)
    int BT = NBLK * 1024;

    char* ws = (char*)d_ws;
    size_t cur = 0;
    auto carve = [&](size_t bytes) -> void* {
        void* p = ws + cur;
        cur += (bytes + 255) & ~(size_t)255;
        return p;
    };

    // ---- primary: LDS-ranked binning + fused LDS-CSR bucket gather ----
    {
        size_t save = cur;
        int2*   coarse    = (int2*)carve((size_t)ND * NBLK * CELL * 8);
        int*    cellcnt   = (int*)carve((size_t)ND * NBLK * 4);
        int4*   ovf       = (int4*)carve((size_t)OVF_CAP * 16);
        int*    ovf_count = (int*)carve(256);
        half8v* supporth  = (half8v*)carve((size_t)N * D_FEAT * 2);
        if (cur <= ws_size && ND <= 512 && NBLK * CELL <= MAXSLOT) {
            (void)hipMemsetAsync(ovf_count, 0, 4, stream);
            int cblocks = (n8 + 1023) / 1024;
            phase1_bin_kernel<<<NBLK + cblocks, 1024, 0, stream>>>(
                (const float4*)support, supporth, rows, cols, vals,
                coarse, cellcnt, ovf, ovf_count, E, BT, NBLK, ND, n8);
            bucket_csr_gather_kernel<<<ND, 1024, 0, stream>>>(
                (const half4v*)supporth, coarse, cellcnt, (float4*)out, NBLK, N);
            ovf_scatter_kernel<<<512, 256, 0, stream>>>(
                support, ovf, ovf_count, out, OVF_CAP);
            return;
        }
        cur = save;
    }

    // ---- fallback 1: R5 fp16 padded buckets (device return-atomics) ----
    {
        size_t save = cur;
        int*    cursor   = (int*)carve((size_t)(N + 1) * 4);
        int2*   pairs    = (int2*)carve((size_t)N * STRIDE * 8);
        int4*   ovf      = (int4*)carve((size_t)8192 * 16);
        half8v* supporth = (half8v*)carve((size_t)N * D_FEAT * 2);
        if (cur <= ws_size) {
            int* ovf_count = cursor + N;
            int bthreads = (E + EPT - 1) / EPT;
            int bblocks = (bthreads + 255) / 256;
            int gstride = bblocks * 256;
            (void)hipMemsetAsync(cursor, 0, (size_t)(N + 1) * 4, stream);
            convert_kernel<<<(n8 + 255) / 256, 256, 0, stream>>>(
                (const float4*)support, supporth, n8);
            bucket_ilp_kernel<<<bblocks, 256, 0, stream>>>(
                rows, cols, vals, cursor, ovf_count, pairs, ovf, E, gstride);
            unsigned int gthreads = (unsigned int)N * 32;
            gather_half_kernel<<<(gthreads + 255) / 256, 256, 0, stream>>>(
                (const half4v*)supporth, cursor, pairs, (float4*)out, N);
            ovf_scatter_kernel<<<512, 256, 0, stream>>>(
                support, ovf, ovf_count, out, 8192);
            return;
        }
        cur = save;
    }

    // ---- fallback 2: atomic scatter ----
    (void)hipMemsetAsync(d_out, 0, (size_t)out_size * sizeof(float), stream);
    unsigned int total = (unsigned int)E * 32;
    gc_scatter_kernel<<<(total + 255) / 256, 256, 0, stream>>>(
        support, vals, rows, cols, out, E);
}